// Round 5
// baseline (749.072 us; speedup 1.0000x reference)
//
#include <hip/hip_runtime.h>
#include <stdint.h>

#define H 512
#define F 1024
#define E 16
#define TOK 8192
#define EPS 1e-5f

typedef short bf16x8 __attribute__((ext_vector_type(8)));
typedef float f32x4 __attribute__((ext_vector_type(4)));

__device__ __forceinline__ float bf2f(unsigned short u) {
    union { unsigned int i; float f; } v; v.i = ((unsigned int)u) << 16; return v.f;
}
__device__ __forceinline__ unsigned short f2bf(float f) {
    union { float f; unsigned int i; } v; v.f = f;
    unsigned int r = (v.i + 0x7FFFu + ((v.i >> 16) & 1u)) >> 16;
    return (unsigned short)r;
}
__device__ __forceinline__ void gload16(const void* g, void* l) {
    __builtin_amdgcn_global_load_lds(
        (const __attribute__((address_space(1))) unsigned int*)g,
        (__attribute__((address_space(3))) unsigned int*)l, 16, 0, 0);
}

// Branch-free erf-GELU: A&S 7.1.26 poly (|err| <= 1.5e-7).
__device__ __forceinline__ float gelu_erf(float v) {
    const float x  = v * 0.70710678118654752f;
    const float ax = fabsf(x);
    const float t  = __builtin_amdgcn_rcpf(fmaf(0.3275911f, ax, 1.0f));
    float p = fmaf(1.061405429f, t, -1.453152027f);
    p = fmaf(p, t, 1.421413741f);
    p = fmaf(p, t, -0.284496736f);
    p = fmaf(p, t, 0.254829592f);
    p = p * t;
    const float ex = __expf(-x * x);
    float er = fmaf(-p, ex, 1.0f);       // erf(|x|)
    er = copysignf(er, x);
    return 0.5f * v * (1.0f + er);
}

// ---------------- Kernel 1: LayerNorm (fp32 tokens -> bf16 xhat) ----------------
__global__ void ln_kernel(const float* __restrict__ tokens,
                          unsigned short* __restrict__ xhat) {
    const int tid  = threadIdx.x;
    const int wid  = tid >> 6;
    const int lane = tid & 63;
    const int token = blockIdx.x * 4 + wid;

    const float* src = tokens + (size_t)token * H + lane * 8;
    float4 r0 = *reinterpret_cast<const float4*>(src);
    float4 r1 = *reinterpret_cast<const float4*>(src + 4);
    float x[8] = {r0.x, r0.y, r0.z, r0.w, r1.x, r1.y, r1.z, r1.w};

    float s = 0.f, s2 = 0.f;
#pragma unroll
    for (int j = 0; j < 8; ++j) { s += x[j]; s2 += x[j] * x[j]; }
#pragma unroll
    for (int m = 32; m >= 1; m >>= 1) {
        s  += __shfl_xor(s, m);
        s2 += __shfl_xor(s2, m);
    }
    const float mu  = s * (1.0f / H);
    float var = s2 * (1.0f / H) - mu * mu;
    var = fmaxf(var, 0.0f);
    const float rstd = rsqrtf(var + EPS);

    unsigned short o[8];
#pragma unroll
    for (int j = 0; j < 8; ++j) o[j] = f2bf((x[j] - mu) * rstd);
    uint4 w;
    w.x = o[0] | ((unsigned)o[1] << 16);
    w.y = o[2] | ((unsigned)o[3] << 16);
    w.z = o[4] | ((unsigned)o[5] << 16);
    w.w = o[6] | ((unsigned)o[7] << 16);
    *reinterpret_cast<uint4*>(xhat + (size_t)token * H + lane * 8) = w;
}

// ---------------- Kernel 2: per-expert 64x64 tiled transpose (fp32 -> bf16) ----
#define XPAD 72
__global__ void transpose_kernel(const float* __restrict__ src,
                                 unsigned short* __restrict__ dst,
                                 int rows, int cols,
                                 const float* __restrict__ scale) {
    __shared__ __align__(16) unsigned short tile[64 * XPAD];
    const int e  = blockIdx.z;
    const int r0 = blockIdx.y * 64;
    const int c0 = blockIdx.x * 64;
    const int tid = threadIdx.x;

    const float* sbase = src + (size_t)e * rows * cols;
    unsigned short* dbase = dst + (size_t)e * rows * cols;

    {
        const int r  = tid >> 2;
        const int cg = (tid & 3) * 16;
        const float* p = sbase + (size_t)(r0 + r) * cols + c0 + cg;
        const float sc = (scale != nullptr) ? scale[e * rows + r0 + r] : 1.0f;
        unsigned short u[16];
#pragma unroll
        for (int j = 0; j < 16; j += 4) {
            float4 v = *reinterpret_cast<const float4*>(p + j);
            u[j + 0] = f2bf(v.x * sc);
            u[j + 1] = f2bf(v.y * sc);
            u[j + 2] = f2bf(v.z * sc);
            u[j + 3] = f2bf(v.w * sc);
        }
#pragma unroll
        for (int j = 0; j < 16; j += 8) {
            uint4 w;
            w.x = u[j + 0] | ((unsigned)u[j + 1] << 16);
            w.y = u[j + 2] | ((unsigned)u[j + 3] << 16);
            w.z = u[j + 4] | ((unsigned)u[j + 5] << 16);
            w.w = u[j + 6] | ((unsigned)u[j + 7] << 16);
            *reinterpret_cast<uint4*>(&tile[r * XPAD + cg + j]) = w;
        }
    }
    __syncthreads();
#pragma unroll
    for (int i = 0; i < 2; ++i) {
        const int oc = (tid >> 3) + i * 32;
        const int og = (tid & 7) * 8;
        unsigned short u[8];
#pragma unroll
        for (int j = 0; j < 8; ++j) u[j] = tile[(og + j) * XPAD + oc];
        uint4 w;
        w.x = u[0] | ((unsigned)u[1] << 16);
        w.y = u[2] | ((unsigned)u[3] << 16);
        w.z = u[4] | ((unsigned)u[5] << 16);
        w.w = u[6] | ((unsigned)u[7] << 16);
        *reinterpret_cast<uint4*>(dbase + (size_t)(c0 + oc) * rows + r0 + og) = w;
    }
}

// ---------------- Kernel 3: b1p[e][f] += b1 + sum_h lnb[e][h]*W1[e][h][f] ------
__global__ void b1fold_kernel(const float* __restrict__ b1,
                              const float* __restrict__ lnb,
                              const float* __restrict__ W1,
                              float* __restrict__ b1p) {
    __shared__ float slb[64];
    const int e = blockIdx.y;
    const int z = blockIdx.z;                  // K chunk 0..7
    const int f = blockIdx.x * 256 + threadIdx.x;
    const int h0 = z * 64;
    if (threadIdx.x < 64) slb[threadIdx.x] = lnb[e * H + h0 + threadIdx.x];
    __syncthreads();
    float acc = (z == 0) ? b1[e * F + f] : 0.0f;
    const float* w = W1 + (size_t)e * H * F + (size_t)h0 * F + f;
#pragma unroll 8
    for (int h = 0; h < 64; ++h) acc += slb[h] * w[(size_t)h * F];
    atomicAdd(&b1p[e * F + f], acc);
}

// ---------------- Kernel 4: GEMM1 + bias + erf-GELU -> h (bf16, in d_out) ------
// tile 256(tok) x 128(F), K=512, 1024 threads (16 waves, 8Mx2N, wave 32x64).
// T3 2-phase pipeline: double-buffered LDS (96 KB), stage(t+1) issued BEFORE
// compute(t); single __syncthreads per kt (its vmcnt(0) drain lands after a
// full compute phase of DMA overlap).  XOR-swizzle both sides (rule #21).
__global__ __launch_bounds__(1024, 4) void gemm1_kernel(
    const unsigned short* __restrict__ xhat,   // [TOK][H] bf16
    const unsigned short* __restrict__ w1gt,   // [E][F][H] bf16 (ln_g folded)
    const float* __restrict__ b1p,             // [E][F]
    unsigned short* __restrict__ hbuf)         // [TOK][E][F] bf16 (= d_out bytes)
{
    __shared__ __align__(16) unsigned short lds_x[2 * 256 * 64];  // 64 KB
    __shared__ __align__(16) unsigned short lds_w[2 * 128 * 64];  // 32 KB

    const int tid  = threadIdx.x;
    const int lane = tid & 63;
    const int w    = tid >> 6;
    const int quad = lane >> 4;
    const int l16  = lane & 15;
    const int swzr = (l16 & 7) * 8;

    const unsigned bid = blockIdx.x;
    const int e  = bid & 15;                  // expert pinned to XCD (bid%8)
    const int t  = bid >> 4;
    const int ft = t & 7;
    const int mt = t >> 3;
    const int m0 = mt * 256, f0 = ft * 128;
    const int wm = w >> 1, wn = w & 1;        // 8 M-slices(32) x 2 N-slices(64)

    f32x4 acc[2][4];
#pragma unroll
    for (int mi = 0; mi < 2; ++mi)
#pragma unroll
        for (int ni = 0; ni < 4; ++ni) acc[mi][ni] = (f32x4){0.f, 0.f, 0.f, 0.f};

    const unsigned short* xg = xhat + (size_t)m0 * H;
    const unsigned short* wg = w1gt + ((size_t)e * F + f0) * H;

    auto stage = [&](int kt, int buf) {
        const int k0 = kt * 64;
#pragma unroll
        for (int i = 0; i < 2; ++i) {          // A: 256 rows x 8 chunks = 2048
            const int idx = tid + i * 1024;
            const int row = idx >> 3;
            const int c   = ((idx & 7) * 8) ^ ((row & 7) * 8);
            gload16(xg + (size_t)row * H + k0 + c,
                    (char*)lds_x + (size_t)buf * 32768 + (size_t)idx * 16);
        }
        {                                       // B: 128 rows x 8 chunks = 1024
            const int row = tid >> 3;
            const int c   = ((tid & 7) * 8) ^ ((row & 7) * 8);
            gload16(wg + (size_t)row * H + k0 + c,
                    (char*)lds_w + (size_t)buf * 16384 + (size_t)tid * 16);
        }
    };

    stage(0, 0);
    __syncthreads();
    for (int kt = 0; kt < 8; ++kt) {
        const int cur = kt & 1;
        if (kt < 7) stage(kt + 1, cur ^ 1);    // fire-and-forget prefetch
#pragma unroll
        for (int ks = 0; ks < 2; ++ks) {
            const int kc = (ks * 32 + quad * 8) ^ swzr;
            bf16x8 a[2], b[4];
#pragma unroll
            for (int mi = 0; mi < 2; ++mi)
                a[mi] = *reinterpret_cast<const bf16x8*>(
                    &lds_x[cur * 16384 + (wm * 32 + mi * 16 + l16) * 64 + kc]);
#pragma unroll
            for (int ni = 0; ni < 4; ++ni)
                b[ni] = *reinterpret_cast<const bf16x8*>(
                    &lds_w[cur * 8192 + (wn * 64 + ni * 16 + l16) * 64 + kc]);
#pragma unroll
            for (int mi = 0; mi < 2; ++mi)
#pragma unroll
                for (int ni = 0; ni < 4; ++ni)
                    acc[mi][ni] = __builtin_amdgcn_mfma_f32_16x16x32_bf16(a[mi], b[ni], acc[mi][ni], 0, 0, 0);
        }
        __syncthreads();                        // drains prefetch; swaps buffers
    }

    // epilogue: bias + erf-GELU, store bf16 h
    float bv[4];
#pragma unroll
    for (int ni = 0; ni < 4; ++ni)
        bv[ni] = b1p[e * F + f0 + wn * 64 + ni * 16 + l16];
#pragma unroll
    for (int mi = 0; mi < 2; ++mi) {
#pragma unroll
        for (int r = 0; r < 4; ++r) {
            const int row = m0 + wm * 32 + mi * 16 + quad * 4 + r;
            unsigned short* dst = hbuf + ((size_t)row * E + e) * F + f0;
#pragma unroll
            for (int ni = 0; ni < 4; ++ni) {
                const float v = acc[mi][ni][r] + bv[ni];
                dst[wn * 64 + ni * 16 + l16] = f2bf(gelu_erf(v));
            }
        }
    }
}

// ---------------- Kernel 5: GEMM2 + bias -> out (fp32, in-place over h) --------
// tile 128(tok) x 512(H out), K=1024, 1024 threads (16 waves, 2Mx8N, wave 64x64).
// T3 2-phase double-buffered pipeline (A 2x16KB + B 2x64KB = 160 KB LDS):
// stage(t+1) overlaps compute(t); ONE barrier per kt.
// FIX vs r4: B stage covers ALL 4096 chunks (i<4) and buffer byte offset is
// 65536 (= 512*64*2B), was 2048 chunks / 32768 B -> uninitialized LDS -> NaN.
// Full-H/full-K per block keeps the in-place h->out overwrite safe.
__global__ __launch_bounds__(1024, 4) void gemm2_kernel(
    const unsigned short* __restrict__ hbuf,   // [TOK][E][F] bf16 (= d_out bytes)
    const unsigned short* __restrict__ w2t,    // [E][H][F] bf16
    const float* __restrict__ b2,              // [E][H]
    float* __restrict__ outp)                  // [TOK][E][H] f32 (= d_out)
{
    __shared__ __align__(16) unsigned short lds_a[2 * 128 * 64];   // 32 KB
    __shared__ __align__(16) unsigned short lds_b[2 * 512 * 64];   // 128 KB

    const int tid  = threadIdx.x;
    const int lane = tid & 63;
    const int w    = tid >> 6;
    const int quad = lane >> 4;
    const int l16  = lane & 15;
    const int swzr = (l16 & 7) * 8;

    const int e  = blockIdx.x & 15;            // expert pinned to XCD
    const int mt = blockIdx.x >> 4;
    const int m0 = mt * 128;
    const int wm = w & 1, wn = w >> 1;         // 2 M-slices(64) x 8 N-slices(64)

    f32x4 acc[4][4];
#pragma unroll
    for (int mi = 0; mi < 4; ++mi)
#pragma unroll
        for (int ni = 0; ni < 4; ++ni) acc[mi][ni] = (f32x4){0.f, 0.f, 0.f, 0.f};

    const unsigned short* hg = hbuf + ((size_t)m0 * E + e) * F;  // row stride E*F
    const unsigned short* wg = w2t + (size_t)e * H * F;

    auto stage = [&](int kt, int buf) {
        const int k0 = kt * 64;
        {                                       // A: 128 rows x 8 chunks = 1024
            const int row = tid >> 3;
            const int c   = ((tid & 7) * 8) ^ ((row & 7) * 8);
            gload16(hg + (size_t)row * (E * F) + k0 + c,
                    (char*)lds_a + (size_t)buf * 16384 + (size_t)tid * 16);
        }
#pragma unroll
        for (int i = 0; i < 4; ++i) {          // B: 512 rows x 8 chunks = 4096
            const int idx = tid + i * 1024;
            const int row = idx >> 3;
            const int c   = ((idx & 7) * 8) ^ ((row & 7) * 8);
            gload16(wg + (size_t)row * F + k0 + c,
                    (char*)lds_b + (size_t)buf * 65536 + (size_t)idx * 16);
        }
    };

    stage(0, 0);
    __syncthreads();
    for (int kt = 0; kt < 16; ++kt) {
        const int cur = kt & 1;
        if (kt < 15) stage(kt + 1, cur ^ 1);   // fire-and-forget prefetch
#pragma unroll
        for (int ks = 0; ks < 2; ++ks) {
            const int kc = (ks * 32 + quad * 8) ^ swzr;
            bf16x8 a[4], b[4];
#pragma unroll
            for (int mi = 0; mi < 4; ++mi)
                a[mi] = *reinterpret_cast<const bf16x8*>(
                    &lds_a[cur * 8192 + (wm * 64 + mi * 16 + l16) * 64 + kc]);
#pragma unroll
            for (int ni = 0; ni < 4; ++ni)
                b[ni] = *reinterpret_cast<const bf16x8*>(
                    &lds_b[cur * 32768 + (wn * 64 + ni * 16 + l16) * 64 + kc]);
#pragma unroll
            for (int ni = 0; ni < 4; ++ni)
#pragma unroll
                for (int mi = 0; mi < 4; ++mi)
                    acc[mi][ni] = __builtin_amdgcn_mfma_f32_16x16x32_bf16(a[mi], b[ni], acc[mi][ni], 0, 0, 0);
        }
        __syncthreads();                        // drains prefetch; swaps buffers
    }

    // epilogue: + b2, fp32 store (overwrites this block's own h region only)
    float bv[4];
#pragma unroll
    for (int ni = 0; ni < 4; ++ni)
        bv[ni] = b2[e * H + wn * 64 + ni * 16 + l16];
#pragma unroll
    for (int mi = 0; mi < 4; ++mi) {
#pragma unroll
        for (int r = 0; r < 4; ++r) {
            const int row = m0 + wm * 64 + mi * 16 + quad * 4 + r;
            float* dst = outp + ((size_t)row * E + e) * H + wn * 64;
#pragma unroll
            for (int ni = 0; ni < 4; ++ni)
                dst[ni * 16 + l16] = acc[mi][ni][r] + bv[ni];
        }
    }
}

// ---------------- launch ----------------
extern "C" void kernel_launch(void* const* d_in, const int* in_sizes, int n_in,
                              void* d_out, int out_size, void* d_ws, size_t ws_size,
                              hipStream_t stream) {
    const float* tokens = (const float*)d_in[0];
    const float* ln_g   = (const float*)d_in[1];
    const float* ln_b   = (const float*)d_in[2];
    const float* W1     = (const float*)d_in[3];
    const float* b1     = (const float*)d_in[4];
    const float* W2     = (const float*)d_in[5];
    const float* b2     = (const float*)d_in[6];

    char* ws = (char*)d_ws;
    // ws layout (42 MB):
    unsigned short* xhat = (unsigned short*)(ws);              //  8,388,608 B
    unsigned short* w1gt = (unsigned short*)(ws + 8388608);    // 16,777,216 B
    unsigned short* w2t  = (unsigned short*)(ws + 25165824);   // 16,777,216 B
    float*          b1p  = (float*)(ws + 41943040);            //     65,536 B

    unsigned short* hbuf = (unsigned short*)d_out;  // h [TOK][E][F] bf16 == out bytes
    float*          outp = (float*)d_out;           // out [TOK][E][H] f32

    hipMemsetAsync(b1p, 0, E * F * sizeof(float), stream);
    hipLaunchKernelGGL(ln_kernel, dim3(TOK / 4), dim3(256), 0, stream, tokens, xhat);
    hipLaunchKernelGGL(transpose_kernel, dim3(F / 64, H / 64, E), dim3(256), 0, stream,
                       W1, w1gt, H, F, ln_g);
    hipLaunchKernelGGL(transpose_kernel, dim3(H / 64, F / 64, E), dim3(256), 0, stream,
                       W2, w2t, F, H, (const float*)nullptr);
    hipLaunchKernelGGL(b1fold_kernel, dim3(F / 256, E, 8), dim3(256), 0, stream, b1, ln_b, W1, b1p);
    hipLaunchKernelGGL(gemm1_kernel, dim3(E * (TOK / 256) * (F / 128)), dim3(1024), 0, stream,
                       xhat, w1gt, b1p, hbuf);
    hipLaunchKernelGGL(gemm2_kernel, dim3(E * (TOK / 128)), dim3(1024), 0, stream,
                       hbuf, w2t, b2, outp);
}

// Round 6
// 670.306 us; speedup vs baseline: 1.1175x; 1.1175x over previous
//
#include <hip/hip_runtime.h>
#include <stdint.h>

#define H 512
#define F 1024
#define E 16
#define TOK 8192
#define EPS 1e-5f

typedef short bf16x8 __attribute__((ext_vector_type(8)));
typedef float f32x4 __attribute__((ext_vector_type(4)));

__device__ __forceinline__ float bf2f(unsigned short u) {
    union { unsigned int i; float f; } v; v.i = ((unsigned int)u) << 16; return v.f;
}
__device__ __forceinline__ unsigned short f2bf(float f) {
    union { float f; unsigned int i; } v; v.f = f;
    unsigned int r = (v.i + 0x7FFFu + ((v.i >> 16) & 1u)) >> 16;
    return (unsigned short)r;
}
__device__ __forceinline__ void gload16(const void* g, void* l) {
    __builtin_amdgcn_global_load_lds(
        (const __attribute__((address_space(1))) unsigned int*)g,
        (__attribute__((address_space(3))) unsigned int*)l, 16, 0, 0);
}

// tanh-form GELU in sigmoid shape: v * sigmoid(1.59577*v + 0.071355*v^3).
// ~8 VALU ops (vs 16 for the erf poly); |diff vs erf-GELU| <= ~3e-4, well
// inside the bf16 absmax budget (threshold 7.97e-2, measured 1.56e-2).
__device__ __forceinline__ float gelu_fast(float v) {
    const float v2 = v * v;
    const float s  = v * fmaf(0.0713548162f, v2, 1.5957691216f);
    const float e  = __expf(-s);
    return v * __builtin_amdgcn_rcpf(1.0f + e);
}

// ---------------- Kernel 1: LayerNorm (fp32 tokens -> bf16 xhat) ----------------
__global__ void ln_kernel(const float* __restrict__ tokens,
                          unsigned short* __restrict__ xhat) {
    const int tid  = threadIdx.x;
    const int wid  = tid >> 6;
    const int lane = tid & 63;
    const int token = blockIdx.x * 4 + wid;

    const float* src = tokens + (size_t)token * H + lane * 8;
    float4 r0 = *reinterpret_cast<const float4*>(src);
    float4 r1 = *reinterpret_cast<const float4*>(src + 4);
    float x[8] = {r0.x, r0.y, r0.z, r0.w, r1.x, r1.y, r1.z, r1.w};

    float s = 0.f, s2 = 0.f;
#pragma unroll
    for (int j = 0; j < 8; ++j) { s += x[j]; s2 += x[j] * x[j]; }
#pragma unroll
    for (int m = 32; m >= 1; m >>= 1) {
        s  += __shfl_xor(s, m);
        s2 += __shfl_xor(s2, m);
    }
    const float mu  = s * (1.0f / H);
    float var = s2 * (1.0f / H) - mu * mu;
    var = fmaxf(var, 0.0f);
    const float rstd = rsqrtf(var + EPS);

    unsigned short o[8];
#pragma unroll
    for (int j = 0; j < 8; ++j) o[j] = f2bf((x[j] - mu) * rstd);
    uint4 w;
    w.x = o[0] | ((unsigned)o[1] << 16);
    w.y = o[2] | ((unsigned)o[3] << 16);
    w.z = o[4] | ((unsigned)o[5] << 16);
    w.w = o[6] | ((unsigned)o[7] << 16);
    *reinterpret_cast<uint4*>(xhat + (size_t)token * H + lane * 8) = w;
}

// ---------------- Kernel 2: per-expert 64x64 tiled transpose (fp32 -> bf16) ----
#define XPAD 72
__global__ void transpose_kernel(const float* __restrict__ src,
                                 unsigned short* __restrict__ dst,
                                 int rows, int cols,
                                 const float* __restrict__ scale) {
    __shared__ __align__(16) unsigned short tile[64 * XPAD];
    const int e  = blockIdx.z;
    const int r0 = blockIdx.y * 64;
    const int c0 = blockIdx.x * 64;
    const int tid = threadIdx.x;

    const float* sbase = src + (size_t)e * rows * cols;
    unsigned short* dbase = dst + (size_t)e * rows * cols;

    {
        const int r  = tid >> 2;
        const int cg = (tid & 3) * 16;
        const float* p = sbase + (size_t)(r0 + r) * cols + c0 + cg;
        const float sc = (scale != nullptr) ? scale[e * rows + r0 + r] : 1.0f;
        unsigned short u[16];
#pragma unroll
        for (int j = 0; j < 16; j += 4) {
            float4 v = *reinterpret_cast<const float4*>(p + j);
            u[j + 0] = f2bf(v.x * sc);
            u[j + 1] = f2bf(v.y * sc);
            u[j + 2] = f2bf(v.z * sc);
            u[j + 3] = f2bf(v.w * sc);
        }
#pragma unroll
        for (int j = 0; j < 16; j += 8) {
            uint4 w;
            w.x = u[j + 0] | ((unsigned)u[j + 1] << 16);
            w.y = u[j + 2] | ((unsigned)u[j + 3] << 16);
            w.z = u[j + 4] | ((unsigned)u[j + 5] << 16);
            w.w = u[j + 6] | ((unsigned)u[j + 7] << 16);
            *reinterpret_cast<uint4*>(&tile[r * XPAD + cg + j]) = w;
        }
    }
    __syncthreads();
#pragma unroll
    for (int i = 0; i < 2; ++i) {
        const int oc = (tid >> 3) + i * 32;
        const int og = (tid & 7) * 8;
        unsigned short u[8];
#pragma unroll
        for (int j = 0; j < 8; ++j) u[j] = tile[(og + j) * XPAD + oc];
        uint4 w;
        w.x = u[0] | ((unsigned)u[1] << 16);
        w.y = u[2] | ((unsigned)u[3] << 16);
        w.z = u[4] | ((unsigned)u[5] << 16);
        w.w = u[6] | ((unsigned)u[7] << 16);
        *reinterpret_cast<uint4*>(dbase + (size_t)(c0 + oc) * rows + r0 + og) = w;
    }
}

// ---------------- Kernel 3: b1p[e][f] += b1 + sum_h lnb[e][h]*W1[e][h][f] ------
__global__ void b1fold_kernel(const float* __restrict__ b1,
                              const float* __restrict__ lnb,
                              const float* __restrict__ W1,
                              float* __restrict__ b1p) {
    __shared__ float slb[64];
    const int e = blockIdx.y;
    const int z = blockIdx.z;                  // K chunk 0..7
    const int f = blockIdx.x * 256 + threadIdx.x;
    const int h0 = z * 64;
    if (threadIdx.x < 64) slb[threadIdx.x] = lnb[e * H + h0 + threadIdx.x];
    __syncthreads();
    float acc = (z == 0) ? b1[e * F + f] : 0.0f;
    const float* w = W1 + (size_t)e * H * F + (size_t)h0 * F + f;
#pragma unroll 8
    for (int h = 0; h < 64; ++h) acc += slb[h] * w[(size_t)h * F];
    atomicAdd(&b1p[e * F + f], acc);
}

// ---------------- Kernel 4: GEMM1 + bias + GELU -> h (bf16, in d_out) ----------
// tile 128(tok) x 128(F), K=512, 512 threads (8 waves, 4Mx2N, wave 32x64).
// dbuf LDS 64 KB -> 2 blocks/CU (cross-block overlap of GELU tail + staging).
// T4 counted-vmcnt 2-deep pipeline: raw s_barrier + s_waitcnt vmcnt(4) (= the
// next stage's in-flight loads), NEVER draining to 0 mid-loop (m218 lever).
__global__ __launch_bounds__(512, 4) void gemm1_kernel(
    const unsigned short* __restrict__ xhat,   // [TOK][H] bf16
    const unsigned short* __restrict__ w1gt,   // [E][F][H] bf16 (ln_g folded)
    const float* __restrict__ b1p,             // [E][F]
    unsigned short* __restrict__ hbuf)         // [TOK][E][F] bf16 (= d_out bytes)
{
    __shared__ __align__(16) unsigned short lds_x[2 * 128 * 64];  // 32 KB
    __shared__ __align__(16) unsigned short lds_w[2 * 128 * 64];  // 32 KB

    const int tid  = threadIdx.x;
    const int lane = tid & 63;
    const int w    = tid >> 6;                 // wave 0..7
    const int quad = lane >> 4;
    const int l16  = lane & 15;
    const int swzr = (l16 & 7) * 8;

    const unsigned bid = blockIdx.x;
    const int e  = bid & 15;                  // expert pinned to XCD (bid%8)
    const int t  = bid >> 4;
    const int ft = t & 7;
    const int mt = t >> 3;
    const int m0 = mt * 128, f0 = ft * 128;
    const int wm = w >> 1, wn = w & 1;        // 4 M-slices(32) x 2 N-slices(64)

    f32x4 acc[2][4];
#pragma unroll
    for (int mi = 0; mi < 2; ++mi)
#pragma unroll
        for (int ni = 0; ni < 4; ++ni) acc[mi][ni] = (f32x4){0.f, 0.f, 0.f, 0.f};

    const unsigned short* xg = xhat + (size_t)m0 * H;
    const unsigned short* wg = w1gt + ((size_t)e * F + f0) * H;

    // 4 loads/thread/stage (2 A + 2 B) -> steady-state wait is vmcnt(4)
    auto stage = [&](int kt, int buf) {
        const int k0 = kt * 64;
#pragma unroll
        for (int i = 0; i < 2; ++i) {          // A: 128 rows x 8 chunks = 1024
            const int idx = tid + i * 512;
            const int row = idx >> 3;
            const int c   = ((idx & 7) * 8) ^ ((row & 7) * 8);
            gload16(xg + (size_t)row * H + k0 + c,
                    (char*)lds_x + (size_t)buf * 16384 + (size_t)idx * 16);
        }
#pragma unroll
        for (int i = 0; i < 2; ++i) {          // B: 128 rows x 8 chunks = 1024
            const int idx = tid + i * 512;
            const int row = idx >> 3;
            const int c   = ((idx & 7) * 8) ^ ((row & 7) * 8);
            gload16(wg + (size_t)row * H + k0 + c,
                    (char*)lds_w + (size_t)buf * 16384 + (size_t)idx * 16);
        }
    };

    stage(0, 0);
    stage(1, 1);
    for (int kt = 0; kt < 8; ++kt) {
        const int cur = kt & 1;
        // wait for stage(kt) only: stage(kt+1)'s 4 loads may stay in flight
        if (kt < 7) asm volatile("s_waitcnt vmcnt(4)" ::: "memory");
        else        asm volatile("s_waitcnt vmcnt(0)" ::: "memory");
        __builtin_amdgcn_s_barrier();          // all waves: buf[cur] ready
#pragma unroll
        for (int ks = 0; ks < 2; ++ks) {
            const int kc = (ks * 32 + quad * 8) ^ swzr;
            bf16x8 a[2], b[4];
#pragma unroll
            for (int mi = 0; mi < 2; ++mi)
                a[mi] = *reinterpret_cast<const bf16x8*>(
                    &lds_x[cur * 8192 + (wm * 32 + mi * 16 + l16) * 64 + kc]);
#pragma unroll
            for (int ni = 0; ni < 4; ++ni)
                b[ni] = *reinterpret_cast<const bf16x8*>(
                    &lds_w[cur * 8192 + (wn * 64 + ni * 16 + l16) * 64 + kc]);
            __builtin_amdgcn_s_setprio(1);
#pragma unroll
            for (int mi = 0; mi < 2; ++mi)
#pragma unroll
                for (int ni = 0; ni < 4; ++ni)
                    acc[mi][ni] = __builtin_amdgcn_mfma_f32_16x16x32_bf16(a[mi], b[ni], acc[mi][ni], 0, 0, 0);
            __builtin_amdgcn_s_setprio(0);
        }
        __builtin_amdgcn_s_barrier();          // all waves done reading buf[cur]
        if (kt + 2 < 8) stage(kt + 2, cur);    // overwrite buf[cur] via DMA
    }

    // epilogue: bias + GELU, store bf16 h
    float bv[4];
#pragma unroll
    for (int ni = 0; ni < 4; ++ni)
        bv[ni] = b1p[e * F + f0 + wn * 64 + ni * 16 + l16];
#pragma unroll
    for (int mi = 0; mi < 2; ++mi) {
#pragma unroll
        for (int r = 0; r < 4; ++r) {
            const int row = m0 + wm * 32 + mi * 16 + quad * 4 + r;
            unsigned short* dst = hbuf + ((size_t)row * E + e) * F + f0;
#pragma unroll
            for (int ni = 0; ni < 4; ++ni) {
                const float v = acc[mi][ni][r] + bv[ni];
                dst[wn * 64 + ni * 16 + l16] = f2bf(gelu_fast(v));
            }
        }
    }
}

// ---------------- Kernel 5: GEMM2 + bias -> out (fp32, in-place over h) --------
// tile 128(tok) x 512(H out), K=1024, 1024 threads (16 waves, 2Mx8N, wave 64x64).
// Same T4 counted-vmcnt 2-deep pipeline (5 loads/thread/stage -> vmcnt(5)).
// LDS A 2x16KB + B 2x64KB = 160 KB, 1 blk/CU; counted waits let loads span
// phases so the 1-blk handicap is mitigated (m218: counted vs drain0 +38-73%).
// Full-H/full-K per block keeps the in-place h->out overwrite safe.
__global__ __launch_bounds__(1024, 4) void gemm2_kernel(
    const unsigned short* __restrict__ hbuf,   // [TOK][E][F] bf16 (= d_out bytes)
    const unsigned short* __restrict__ w2t,    // [E][H][F] bf16
    const float* __restrict__ b2,              // [E][H]
    float* __restrict__ outp)                  // [TOK][E][H] f32 (= d_out)
{
    __shared__ __align__(16) unsigned short lds_a[2 * 128 * 64];   // 32 KB
    __shared__ __align__(16) unsigned short lds_b[2 * 512 * 64];   // 128 KB

    const int tid  = threadIdx.x;
    const int lane = tid & 63;
    const int w    = tid >> 6;
    const int quad = lane >> 4;
    const int l16  = lane & 15;
    const int swzr = (l16 & 7) * 8;

    const int e  = blockIdx.x & 15;            // expert pinned to XCD
    const int mt = blockIdx.x >> 4;
    const int m0 = mt * 128;
    const int wm = w & 1, wn = w >> 1;         // 2 M-slices(64) x 8 N-slices(64)

    f32x4 acc[4][4];
#pragma unroll
    for (int mi = 0; mi < 4; ++mi)
#pragma unroll
        for (int ni = 0; ni < 4; ++ni) acc[mi][ni] = (f32x4){0.f, 0.f, 0.f, 0.f};

    const unsigned short* hg = hbuf + ((size_t)m0 * E + e) * F;  // row stride E*F
    const unsigned short* wg = w2t + (size_t)e * H * F;

    // 5 loads/thread/stage (1 A + 4 B) -> steady-state wait is vmcnt(5)
    auto stage = [&](int kt, int buf) {
        const int k0 = kt * 64;
        {                                       // A: 128 rows x 8 chunks = 1024
            const int row = tid >> 3;
            const int c   = ((tid & 7) * 8) ^ ((row & 7) * 8);
            gload16(hg + (size_t)row * (E * F) + k0 + c,
                    (char*)lds_a + (size_t)buf * 16384 + (size_t)tid * 16);
        }
#pragma unroll
        for (int i = 0; i < 4; ++i) {          // B: 512 rows x 8 chunks = 4096
            const int idx = tid + i * 1024;
            const int row = idx >> 3;
            const int c   = ((idx & 7) * 8) ^ ((row & 7) * 8);
            gload16(wg + (size_t)row * F + k0 + c,
                    (char*)lds_b + (size_t)buf * 65536 + (size_t)idx * 16);
        }
    };

    stage(0, 0);
    stage(1, 1);
    for (int kt = 0; kt < 16; ++kt) {
        const int cur = kt & 1;
        if (kt < 15) asm volatile("s_waitcnt vmcnt(5)" ::: "memory");
        else         asm volatile("s_waitcnt vmcnt(0)" ::: "memory");
        __builtin_amdgcn_s_barrier();          // all waves: buf[cur] ready
#pragma unroll
        for (int ks = 0; ks < 2; ++ks) {
            const int kc = (ks * 32 + quad * 8) ^ swzr;
            bf16x8 a[4], b[4];
#pragma unroll
            for (int mi = 0; mi < 4; ++mi)
                a[mi] = *reinterpret_cast<const bf16x8*>(
                    &lds_a[cur * 8192 + (wm * 64 + mi * 16 + l16) * 64 + kc]);
#pragma unroll
            for (int ni = 0; ni < 4; ++ni)
                b[ni] = *reinterpret_cast<const bf16x8*>(
                    &lds_b[cur * 32768 + (wn * 64 + ni * 16 + l16) * 64 + kc]);
            __builtin_amdgcn_s_setprio(1);
#pragma unroll
            for (int ni = 0; ni < 4; ++ni)
#pragma unroll
                for (int mi = 0; mi < 4; ++mi)
                    acc[mi][ni] = __builtin_amdgcn_mfma_f32_16x16x32_bf16(a[mi], b[ni], acc[mi][ni], 0, 0, 0);
            __builtin_amdgcn_s_setprio(0);
        }
        __builtin_amdgcn_s_barrier();          // all waves done reading buf[cur]
        if (kt + 2 < 16) stage(kt + 2, cur);   // overwrite buf[cur] via DMA
    }

    // epilogue: + b2, fp32 store (overwrites this block's own h region only)
    float bv[4];
#pragma unroll
    for (int ni = 0; ni < 4; ++ni)
        bv[ni] = b2[e * H + wn * 64 + ni * 16 + l16];
#pragma unroll
    for (int mi = 0; mi < 4; ++mi) {
#pragma unroll
        for (int r = 0; r < 4; ++r) {
            const int row = m0 + wm * 64 + mi * 16 + quad * 4 + r;
            float* dst = outp + ((size_t)row * E + e) * H + wn * 64;
#pragma unroll
            for (int ni = 0; ni < 4; ++ni)
                dst[ni * 16 + l16] = acc[mi][ni][r] + bv[ni];
        }
    }
}

// ---------------- launch ----------------
extern "C" void kernel_launch(void* const* d_in, const int* in_sizes, int n_in,
                              void* d_out, int out_size, void* d_ws, size_t ws_size,
                              hipStream_t stream) {
    const float* tokens = (const float*)d_in[0];
    const float* ln_g   = (const float*)d_in[1];
    const float* ln_b   = (const float*)d_in[2];
    const float* W1     = (const float*)d_in[3];
    const float* b1     = (const float*)d_in[4];
    const float* W2     = (const float*)d_in[5];
    const float* b2     = (const float*)d_in[6];

    char* ws = (char*)d_ws;
    // ws layout (42 MB):
    unsigned short* xhat = (unsigned short*)(ws);              //  8,388,608 B
    unsigned short* w1gt = (unsigned short*)(ws + 8388608);    // 16,777,216 B
    unsigned short* w2t  = (unsigned short*)(ws + 25165824);   // 16,777,216 B
    float*          b1p  = (float*)(ws + 41943040);            //     65,536 B

    unsigned short* hbuf = (unsigned short*)d_out;  // h [TOK][E][F] bf16 == out bytes
    float*          outp = (float*)d_out;           // out [TOK][E][H] f32

    hipMemsetAsync(b1p, 0, E * F * sizeof(float), stream);
    hipLaunchKernelGGL(ln_kernel, dim3(TOK / 4), dim3(256), 0, stream, tokens, xhat);
    hipLaunchKernelGGL(transpose_kernel, dim3(F / 64, H / 64, E), dim3(256), 0, stream,
                       W1, w1gt, H, F, ln_g);
    hipLaunchKernelGGL(transpose_kernel, dim3(H / 64, F / 64, E), dim3(256), 0, stream,
                       W2, w2t, F, H, (const float*)nullptr);
    hipLaunchKernelGGL(b1fold_kernel, dim3(F / 256, E, 8), dim3(256), 0, stream, b1, ln_b, W1, b1p);
    hipLaunchKernelGGL(gemm1_kernel, dim3(E * (TOK / 128) * (F / 128)), dim3(512), 0, stream,
                       xhat, w1gt, b1p, hbuf);
    hipLaunchKernelGGL(gemm2_kernel, dim3(E * (TOK / 128)), dim3(1024), 0, stream,
                       hbuf, w2t, b2, outp);
}